// Round 1
// baseline (964.198 us; speedup 1.0000x reference)
//
#include <hip/hip_runtime.h>
#include <math.h>

#define NN 50000      // nodes
#define DD 128        // embedding dim
#define K2D 256       // 2*D (pair width / GEMM K)
#define HH 256        // hidden
#define EE 400000     // edges

#define TE 64         // edges (or nodes) per block tile
#define PST 260       // padded LDS row stride in floats (260*4B, 16B-aligned)
#define TAU 1e-3f     // |z| below this -> fp64 recheck

// ---------------------------------------------------------------------------
// Detector: per-edge z = relu(pair@Wd1 + bd1)@Wd2 + bd2 ; score = sigmoid(z).
// 256 threads, tile = 64 edges x 256 hidden cols, 8x8 micro-tile per thread.
// ---------------------------------------------------------------------------
__global__ __launch_bounds__(256) void det_kernel(
    const float* __restrict__ emb,
    const int* __restrict__ srcIdx, const int* __restrict__ dstIdx,
    const float* __restrict__ W1, const float* __restrict__ b1,
    const float* __restrict__ W2, const float* __restrict__ b2p,
    float* __restrict__ scores,
    int* __restrict__ last,
    int* __restrict__ flagCount, int* __restrict__ flagList, int flagCap)
{
    __shared__ __align__(16) float P[TE * PST];
    const int tid = threadIdx.x;
    const int e0 = blockIdx.x * TE;

    // Stage pair tile: P[i][0:128]=emb[src], P[i][128:256]=emb[dst]
    {
        const int i = tid >> 2;
        const int q = tid & 3;
        const int e = e0 + i;
        const int node = (q < 2) ? srcIdx[e] : dstIdx[e];
        const float4* s4 = (const float4*)(emb + node * DD + (q & 1) * 64);
        float4* d4 = (float4*)(P + i * PST + q * 64);
#pragma unroll
        for (int t = 0; t < 16; ++t) d4[t] = s4[t];
    }
    __syncthreads();

    const int rowg = tid >> 5;   // 0..7 : owns rows rowg*8 .. +7
    const int colg = tid & 31;   // 0..31: owns cols colg*8 .. +7
    const int c0 = colg * 8;

    float acc[8][8];
#pragma unroll
    for (int c = 0; c < 8; ++c) {
        const float bv = b1[c0 + c];
#pragma unroll
        for (int r = 0; r < 8; ++r) acc[r][c] = bv;
    }

    for (int kk = 0; kk < K2D; kk += 4) {
        float af[8][4];
#pragma unroll
        for (int r = 0; r < 8; ++r) {
            const float4 v = *(const float4*)&P[(rowg * 8 + r) * PST + kk];
            af[r][0] = v.x; af[r][1] = v.y; af[r][2] = v.z; af[r][3] = v.w;
        }
#pragma unroll
        for (int dk = 0; dk < 4; ++dk) {
            const float4 w0 = *(const float4*)&W1[(kk + dk) * HH + c0];
            const float4 w1 = *(const float4*)&W1[(kk + dk) * HH + c0 + 4];
#pragma unroll
            for (int r = 0; r < 8; ++r) {
                const float av = af[r][dk];
                acc[r][0] = fmaf(av, w0.x, acc[r][0]);
                acc[r][1] = fmaf(av, w0.y, acc[r][1]);
                acc[r][2] = fmaf(av, w0.z, acc[r][2]);
                acc[r][3] = fmaf(av, w0.w, acc[r][3]);
                acc[r][4] = fmaf(av, w1.x, acc[r][4]);
                acc[r][5] = fmaf(av, w1.y, acc[r][5]);
                acc[r][6] = fmaf(av, w1.z, acc[r][6]);
                acc[r][7] = fmaf(av, w1.w, acc[r][7]);
            }
        }
    }

    // Layer 2 partials: pz[r] = sum over my 8 cols of relu(h)*W2[c]
    float w2[8];
#pragma unroll
    for (int c = 0; c < 8; ++c) w2[c] = W2[c0 + c];

    float pz[8];
#pragma unroll
    for (int r = 0; r < 8; ++r) {
        float s = 0.f;
#pragma unroll
        for (int c = 0; c < 8; ++c) s = fmaf(fmaxf(acc[r][c], 0.f), w2[c], s);
        pz[r] = s;
    }
    // butterfly reduce across the 32 col-group lanes (stays within half-wave)
#pragma unroll
    for (int m = 1; m <= 16; m <<= 1) {
#pragma unroll
        for (int r = 0; r < 8; ++r) pz[r] += __shfl_xor(pz[r], m, 64);
    }

    if (colg == 0) {
        const float b2v = *b2p;
        for (int r = 0; r < 8; ++r) {
            const int e = e0 + rowg * 8 + r;
            const float z = pz[r] + b2v;
            scores[e] = 1.0f / (1.0f + expf(-z));
            bool deferred = false;
            if (fabsf(z) < TAU) {
                const int slot = atomicAdd(flagCount, 1);
                if (slot < flagCap) { flagList[slot] = e; deferred = true; }
            }
            if (!deferred && z > 0.0f) {
                atomicMax(&last[srcIdx[e]], e + 1);
                atomicMax(&last[dstIdx[e]], e + 1);
            }
        }
    }
}

// ---------------------------------------------------------------------------
// fp64 recheck for near-boundary edges. One 64-lane block per flagged edge,
// grid-stride (count known only on device). fp32*fp32 exact in fp64.
// ---------------------------------------------------------------------------
__global__ __launch_bounds__(64) void recheck_kernel(
    const float* __restrict__ emb,
    const int* __restrict__ srcIdx, const int* __restrict__ dstIdx,
    const float* __restrict__ W1, const float* __restrict__ b1,
    const float* __restrict__ W2, const float* __restrict__ b2p,
    int* __restrict__ last,
    const int* __restrict__ flagCount, const int* __restrict__ flagList,
    int flagCap)
{
    __shared__ float pair[K2D];
    const int lane = threadIdx.x;
    const int cnt = min(*flagCount, flagCap);
    for (int f = blockIdx.x; f < cnt; f += gridDim.x) {
        const int e = flagList[f];
        const int s = srcIdx[e], d = dstIdx[e];
        __syncthreads();
        for (int t = lane; t < K2D; t += 64)
            pair[t] = (t < DD) ? emb[s * DD + t] : emb[d * DD + t - DD];
        __syncthreads();
        double zp = 0.0;
        for (int jj = 0; jj < 4; ++jj) {
            const int j = lane + jj * 64;
            double h = (double)b1[j];
            for (int k = 0; k < K2D; ++k)
                h += (double)pair[k] * (double)W1[k * HH + j];
            if (h > 0.0) zp += h * (double)W2[j];
        }
#pragma unroll
        for (int m = 1; m <= 32; m <<= 1) zp += __shfl_xor(zp, m, 64);
        if (lane == 0) {
            const double z = zp + (double)(*b2p);
            if (z > 0.0) {
                atomicMax(&last[s], e + 1);
                atomicMax(&last[d], e + 1);
            }
        }
        __syncthreads();
    }
}

// ---------------------------------------------------------------------------
// Resolver: per NODE, for the winning edge only.
// layer1: pair@Wr1+br1, relu -> h (stored back into the same LDS tile)
// layer2: h@Wr2+br2 -> res(128) ; out = last>0 ? (emb+res)*0.5 : emb
// ---------------------------------------------------------------------------
__global__ __launch_bounds__(256) void res_kernel(
    const float* __restrict__ emb,
    const int* __restrict__ srcIdx, const int* __restrict__ dstIdx,
    const float* __restrict__ W1, const float* __restrict__ b1,
    const float* __restrict__ W2, const float* __restrict__ b2,
    const int* __restrict__ last,
    float* __restrict__ outRes)
{
    __shared__ __align__(16) float P[TE * PST];
    const int tid = threadIdx.x;
    const int n0 = blockIdx.x * TE;

    {
        const int i = tid >> 2;
        const int q = tid & 3;
        const int n = n0 + i;
        int e = 0;
        if (n < NN) { const int l = last[n]; if (l > 0) e = l - 1; }
        const int node = (q < 2) ? srcIdx[e] : dstIdx[e];
        const float4* s4 = (const float4*)(emb + node * DD + (q & 1) * 64);
        float4* d4 = (float4*)(P + i * PST + q * 64);
#pragma unroll
        for (int t = 0; t < 16; ++t) d4[t] = s4[t];
    }
    __syncthreads();

    const int rowg = tid >> 5;
    const int colg = tid & 31;

    // ---- layer 1 (same micro-tile as detector) ----
    {
        const int c0 = colg * 8;
        float acc[8][8];
#pragma unroll
        for (int c = 0; c < 8; ++c) {
            const float bv = b1[c0 + c];
#pragma unroll
            for (int r = 0; r < 8; ++r) acc[r][c] = bv;
        }
        for (int kk = 0; kk < K2D; kk += 4) {
            float af[8][4];
#pragma unroll
            for (int r = 0; r < 8; ++r) {
                const float4 v = *(const float4*)&P[(rowg * 8 + r) * PST + kk];
                af[r][0] = v.x; af[r][1] = v.y; af[r][2] = v.z; af[r][3] = v.w;
            }
#pragma unroll
            for (int dk = 0; dk < 4; ++dk) {
                const float4 w0 = *(const float4*)&W1[(kk + dk) * HH + c0];
                const float4 w1 = *(const float4*)&W1[(kk + dk) * HH + c0 + 4];
#pragma unroll
                for (int r = 0; r < 8; ++r) {
                    const float av = af[r][dk];
                    acc[r][0] = fmaf(av, w0.x, acc[r][0]);
                    acc[r][1] = fmaf(av, w0.y, acc[r][1]);
                    acc[r][2] = fmaf(av, w0.z, acc[r][2]);
                    acc[r][3] = fmaf(av, w0.w, acc[r][3]);
                    acc[r][4] = fmaf(av, w1.x, acc[r][4]);
                    acc[r][5] = fmaf(av, w1.y, acc[r][5]);
                    acc[r][6] = fmaf(av, w1.z, acc[r][6]);
                    acc[r][7] = fmaf(av, w1.w, acc[r][7]);
                }
            }
        }
        __syncthreads();   // everyone done READING pair tile
        // write h = relu(acc) back over the tile
#pragma unroll
        for (int r = 0; r < 8; ++r) {
            float4 h0, h1;
            h0.x = fmaxf(acc[r][0], 0.f); h0.y = fmaxf(acc[r][1], 0.f);
            h0.z = fmaxf(acc[r][2], 0.f); h0.w = fmaxf(acc[r][3], 0.f);
            h1.x = fmaxf(acc[r][4], 0.f); h1.y = fmaxf(acc[r][5], 0.f);
            h1.z = fmaxf(acc[r][6], 0.f); h1.w = fmaxf(acc[r][7], 0.f);
            *(float4*)&P[(rowg * 8 + r) * PST + c0] = h0;
            *(float4*)&P[(rowg * 8 + r) * PST + c0 + 4] = h1;
        }
        __syncthreads();
    }

    // ---- layer 2: (64 x 256) @ (256 x 128) ----
    const int c0b = colg * 4;
    float acc2[8][4];
#pragma unroll
    for (int c = 0; c < 4; ++c) {
        const float bv = b2[c0b + c];
#pragma unroll
        for (int r = 0; r < 8; ++r) acc2[r][c] = bv;
    }
    for (int kk = 0; kk < HH; kk += 4) {
        float af[8][4];
#pragma unroll
        for (int r = 0; r < 8; ++r) {
            const float4 v = *(const float4*)&P[(rowg * 8 + r) * PST + kk];
            af[r][0] = v.x; af[r][1] = v.y; af[r][2] = v.z; af[r][3] = v.w;
        }
#pragma unroll
        for (int dk = 0; dk < 4; ++dk) {
            const float4 w = *(const float4*)&W2[(kk + dk) * DD + c0b];
#pragma unroll
            for (int r = 0; r < 8; ++r) {
                const float av = af[r][dk];
                acc2[r][0] = fmaf(av, w.x, acc2[r][0]);
                acc2[r][1] = fmaf(av, w.y, acc2[r][1]);
                acc2[r][2] = fmaf(av, w.z, acc2[r][2]);
                acc2[r][3] = fmaf(av, w.w, acc2[r][3]);
            }
        }
    }

#pragma unroll
    for (int r = 0; r < 8; ++r) {
        const int n = n0 + rowg * 8 + r;
        if (n >= NN) continue;
        const int l = last[n];
        const float4 ev = *(const float4*)&emb[n * DD + c0b];
        float4 o;
        if (l > 0) {
            o.x = (ev.x + acc2[r][0]) * 0.5f;
            o.y = (ev.y + acc2[r][1]) * 0.5f;
            o.z = (ev.z + acc2[r][2]) * 0.5f;
            o.w = (ev.w + acc2[r][3]) * 0.5f;
        } else {
            o = ev;
        }
        *(float4*)&outRes[n * DD + c0b] = o;
    }
}

// ---------------------------------------------------------------------------
extern "C" void kernel_launch(void* const* d_in, const int* in_sizes, int n_in,
                              void* d_out, int out_size, void* d_ws, size_t ws_size,
                              hipStream_t stream)
{
    const float* emb = (const float*)d_in[0];
    const int*   edge = (const int*)d_in[1];
    const float* Wd1 = (const float*)d_in[2];
    const float* bd1 = (const float*)d_in[3];
    const float* Wd2 = (const float*)d_in[4];
    const float* bd2 = (const float*)d_in[5];
    const float* Wr1 = (const float*)d_in[6];
    const float* br1 = (const float*)d_in[7];
    const float* Wr2 = (const float*)d_in[8];
    const float* br2 = (const float*)d_in[9];

    const int* srcIdx = edge;
    const int* dstIdx = edge + EE;

    float* outRes = (float*)d_out;
    float* scores = outRes + (size_t)NN * DD;

    int* last      = (int*)d_ws;
    int* flagCount = last + NN;
    int* flagList  = flagCount + 64;
    long wsInts = (long)(ws_size / 4);
    long capL = wsInts - NN - 64;
    int flagCap = (capL > 262144L) ? 262144 : (capL < 0 ? 0 : (int)capL);

    // zero `last` (scatter-max init) + flagCount each call (ws is not re-poisoned)
    hipMemsetAsync(d_ws, 0, (NN + 64) * sizeof(int), stream);

    det_kernel<<<EE / TE, 256, 0, stream>>>(emb, srcIdx, dstIdx,
                                            Wd1, bd1, Wd2, bd2,
                                            scores, last, flagCount, flagList, flagCap);
    recheck_kernel<<<256, 64, 0, stream>>>(emb, srcIdx, dstIdx,
                                           Wd1, bd1, Wd2, bd2,
                                           last, flagCount, flagList, flagCap);
    res_kernel<<<(NN + TE - 1) / TE, 256, 0, stream>>>(emb, srcIdx, dstIdx,
                                                       Wr1, br1, Wr2, br2,
                                                       last, outRes);
}

// Round 2
// 668.555 us; speedup vs baseline: 1.4422x; 1.4422x over previous
//
#include <hip/hip_runtime.h>
#include <math.h>

#define NN 50000      // nodes
#define DD 128        // embedding dim
#define K2D 256       // 2*D (pair width / GEMM K)
#define HH 256        // hidden
#define EE 400000     // edges
#define TE 64         // rows (edges or nodes) per block
#define TAU 0.02f     // |z| below this -> fp64 recheck (bf16 z error sigma ~3e-3)

typedef __attribute__((ext_vector_type(8))) short bf16x8;
typedef __attribute__((ext_vector_type(4))) float f32x4;
typedef unsigned int uint;
typedef unsigned short ushort;

__device__ __forceinline__ ushort f2bf(float x) {
    uint u = __builtin_bit_cast(uint, x);
    u = (u + 0x7FFFu + ((u >> 16) & 1u)) >> 16;   // RNE
    return (ushort)u;
}

// LDS A-tile is stored directly in MFMA A-fragment order:
// element (row r in [0,64), k in [0,256)) lives at
//   ((r>>4)*8 + (k>>5))*512 + (((k>>3)&3)*16 + (r&15))*8 + (k&7)
// so wave-local a-frag (mtile m, ktile t) = ds_read_b128 at (m*8+t)*512 + lane*8.
__device__ __forceinline__ int stageOff(int r, int k) {
    return ((r >> 4) * 8 + (k >> 5)) * 512 + ((((k >> 3) & 3) << 4) + (r & 15)) * 8 + (k & 7);
}

// ---------------------------------------------------------------------------
// Weight swizzle: W (K x N, fp32 row-major) -> bf16 MFMA B-frag order:
// out[((n*Kt + t)*64 + lane)*8 + j] = W[t*32 + (lane>>4)*8 + j][n*16 + (lane&15)]
// ---------------------------------------------------------------------------
__global__ __launch_bounds__(64) void swz_kernel(const float* __restrict__ W,
                                                 ushort* __restrict__ out,
                                                 int N, int Kt)
{
    const int bid = blockIdx.x;
    const int n = bid / Kt, t = bid - n * Kt;
    const int l = threadIdx.x;
    const int row0 = t * 32 + (l >> 4) * 8;
    const int col = n * 16 + (l & 15);
    ushort tmp[8];
#pragma unroll
    for (int j = 0; j < 8; ++j) tmp[j] = f2bf(W[(row0 + j) * N + col]);
    uint4 p;
    p.x = (uint)tmp[0] | ((uint)tmp[1] << 16);
    p.y = (uint)tmp[2] | ((uint)tmp[3] << 16);
    p.z = (uint)tmp[4] | ((uint)tmp[5] << 16);
    p.w = (uint)tmp[6] | ((uint)tmp[7] << 16);
    *(uint4*)(out + ((size_t)bid * 64 + l) * 8) = p;
}

// ---------------------------------------------------------------------------
// Detector: z = relu(pair@Wd1+b1)@Wd2+b2 via bf16 MFMA; flag |z|<TAU for fp64.
// 256 thr = 4 waves; block tile 64 edges x 256 cols; wave owns N=64.
// ---------------------------------------------------------------------------
__global__ __launch_bounds__(256) void det_kernel(
    const float* __restrict__ emb,
    const int* __restrict__ srcIdx, const int* __restrict__ dstIdx,
    const ushort* __restrict__ w1s, const float* __restrict__ b1,
    const float* __restrict__ W2, const float* __restrict__ b2p,
    float* __restrict__ scores,
    int* __restrict__ last,
    int* __restrict__ flagCount, int* __restrict__ flagList, int flagCap)
{
    __shared__ __align__(16) ushort A_lds[TE * K2D];   // 32 KB, frag order
    __shared__ float zp[256];
    const int tid = threadIdx.x;
    const int e0 = blockIdx.x * TE;

    // ---- stage pair tile (fp32 -> bf16, frag order) ----
    {
        const int r = tid >> 2, q = tid & 3;
        const int e = e0 + r;
        const int node = (q < 2) ? srcIdx[e] : dstIdx[e];
        const float4* s4 = (const float4*)(emb + (size_t)node * DD + (q & 1) * 64);
#pragma unroll
        for (int u = 0; u < 16; ++u) {
            const float4 v = s4[u];
            const int k0 = q * 64 + u * 4;
            uint2 p;
            p.x = (uint)f2bf(v.x) | ((uint)f2bf(v.y) << 16);
            p.y = (uint)f2bf(v.z) | ((uint)f2bf(v.w) << 16);
            *(uint2*)&A_lds[stageOff(r, k0)] = p;
        }
    }
    __syncthreads();

    const int wv = tid >> 6;
    const int lane = tid & 63;
    const int lc = lane & 15, lg = lane >> 4;

    f32x4 acc[4][4] = {};
    const ushort* wbase = w1s + (size_t)(wv * 4) * 8 * 512;

#pragma unroll 2
    for (int t = 0; t < 8; ++t) {
        bf16x8 af[4], bfr[4];
#pragma unroll
        for (int m = 0; m < 4; ++m)
            af[m] = *(const bf16x8*)&A_lds[(m * 8 + t) * 512 + lane * 8];
#pragma unroll
        for (int n = 0; n < 4; ++n)
            bfr[n] = *(const bf16x8*)(wbase + (n * 8 + t) * 512 + lane * 8);
#pragma unroll
        for (int m = 0; m < 4; ++m)
#pragma unroll
            for (int n = 0; n < 4; ++n)
                acc[m][n] = __builtin_amdgcn_mfma_f32_16x16x32_bf16(af[m], bfr[n], acc[m][n], 0, 0, 0);
    }

    // ---- layer 2 in fp32: pz[row] = sum_cols relu(h+b1)*W2 ----
    float b1v[4], w2v[4];
#pragma unroll
    for (int n = 0; n < 4; ++n) {
        const int col = wv * 64 + n * 16 + lc;
        b1v[n] = b1[col];
        w2v[n] = W2[col];
    }
    float pz[4][4];
#pragma unroll
    for (int m = 0; m < 4; ++m)
#pragma unroll
        for (int r = 0; r < 4; ++r) {
            float s = 0.f;
#pragma unroll
            for (int n = 0; n < 4; ++n)
                s = fmaf(fmaxf(acc[m][n][r] + b1v[n], 0.f), w2v[n], s);
            pz[m][r] = s;
        }
#pragma unroll
    for (int msk = 1; msk <= 8; msk <<= 1)
#pragma unroll
        for (int m = 0; m < 4; ++m)
#pragma unroll
            for (int r = 0; r < 4; ++r)
                pz[m][r] += __shfl_xor(pz[m][r], msk, 64);
    if (lc == 0) {
#pragma unroll
        for (int m = 0; m < 4; ++m)
#pragma unroll
            for (int r = 0; r < 4; ++r)
                zp[wv * 64 + m * 16 + lg * 4 + r] = pz[m][r];
    }
    __syncthreads();

    if (tid < 64) {
        const int e = e0 + tid;
        const float z = zp[tid] + zp[64 + tid] + zp[128 + tid] + zp[192 + tid] + *b2p;
        scores[e] = 1.0f / (1.0f + expf(-z));
        bool deferred = false;
        if (fabsf(z) < TAU) {
            const int slot = atomicAdd(flagCount, 1);
            if (slot < flagCap) { flagList[slot] = e; deferred = true; }
        }
        if (!deferred && z > 0.0f) {
            atomicMax(&last[srcIdx[e]], e + 1);
            atomicMax(&last[dstIdx[e]], e + 1);
        }
    }
}

// ---------------------------------------------------------------------------
// fp64 recheck of near-boundary edges (exact sign decision).
// ---------------------------------------------------------------------------
__global__ __launch_bounds__(64) void recheck_kernel(
    const float* __restrict__ emb,
    const int* __restrict__ srcIdx, const int* __restrict__ dstIdx,
    const float* __restrict__ W1, const float* __restrict__ b1,
    const float* __restrict__ W2, const float* __restrict__ b2p,
    int* __restrict__ last,
    const int* __restrict__ flagCount, const int* __restrict__ flagList,
    int flagCap)
{
    __shared__ float pair[K2D];
    const int lane = threadIdx.x;
    const int cnt = min(*flagCount, flagCap);
    for (int f = blockIdx.x; f < cnt; f += gridDim.x) {
        const int e = flagList[f];
        const int s = srcIdx[e], d = dstIdx[e];
        __syncthreads();
        for (int t = lane; t < K2D; t += 64)
            pair[t] = (t < DD) ? emb[(size_t)s * DD + t] : emb[(size_t)d * DD + t - DD];
        __syncthreads();
        double zpart = 0.0;
        for (int jj = 0; jj < 4; ++jj) {
            const int j = lane + jj * 64;
            double h = (double)b1[j];
            for (int k = 0; k < K2D; ++k)
                h += (double)pair[k] * (double)W1[k * HH + j];
            if (h > 0.0) zpart += h * (double)W2[j];
        }
#pragma unroll
        for (int m = 1; m <= 32; m <<= 1) zpart += __shfl_xor(zpart, m, 64);
        if (lane == 0) {
            const double z = zpart + (double)(*b2p);
            if (z > 0.0) {
                atomicMax(&last[s], e + 1);
                atomicMax(&last[d], e + 1);
            }
        }
        __syncthreads();
    }
}

// ---------------------------------------------------------------------------
// Resolver per NODE (winning edge only), both layers bf16 MFMA.
// ---------------------------------------------------------------------------
__global__ __launch_bounds__(256) void res_kernel(
    const float* __restrict__ emb,
    const int* __restrict__ srcIdx, const int* __restrict__ dstIdx,
    const ushort* __restrict__ w1s, const float* __restrict__ b1,
    const ushort* __restrict__ w2s, const float* __restrict__ b2,
    const int* __restrict__ last,
    float* __restrict__ outRes)
{
    __shared__ __align__(16) ushort A_lds[TE * K2D];   // pair tile, then h tile
    __shared__ int lastL[TE];
    const int tid = threadIdx.x;
    const int n0 = blockIdx.x * TE;

    if (tid < TE) {
        const int n = n0 + tid;
        lastL[tid] = (n < NN) ? last[n] : 0;
    }
    // ---- stage pair tile for winning edges ----
    {
        const int r = tid >> 2, q = tid & 3;
        const int n = n0 + r;
        int e = 0;
        if (n < NN) { const int l = last[n]; if (l > 0) e = l - 1; }
        const int node = (q < 2) ? srcIdx[e] : dstIdx[e];
        const float4* s4 = (const float4*)(emb + (size_t)node * DD + (q & 1) * 64);
#pragma unroll
        for (int u = 0; u < 16; ++u) {
            const float4 v = s4[u];
            const int k0 = q * 64 + u * 4;
            uint2 p;
            p.x = (uint)f2bf(v.x) | ((uint)f2bf(v.y) << 16);
            p.y = (uint)f2bf(v.z) | ((uint)f2bf(v.w) << 16);
            *(uint2*)&A_lds[stageOff(r, k0)] = p;
        }
    }
    __syncthreads();

    const int wv = tid >> 6;
    const int lane = tid & 63;
    const int lc = lane & 15, lg = lane >> 4;

    // ---- layer 1 MFMA ----
    f32x4 acc[4][4] = {};
    {
        const ushort* wbase = w1s + (size_t)(wv * 4) * 8 * 512;
#pragma unroll 2
        for (int t = 0; t < 8; ++t) {
            bf16x8 af[4], bfr[4];
#pragma unroll
            for (int m = 0; m < 4; ++m)
                af[m] = *(const bf16x8*)&A_lds[(m * 8 + t) * 512 + lane * 8];
#pragma unroll
            for (int n = 0; n < 4; ++n)
                bfr[n] = *(const bf16x8*)(wbase + (n * 8 + t) * 512 + lane * 8);
#pragma unroll
            for (int m = 0; m < 4; ++m)
#pragma unroll
                for (int n = 0; n < 4; ++n)
                    acc[m][n] = __builtin_amdgcn_mfma_f32_16x16x32_bf16(af[m], bfr[n], acc[m][n], 0, 0, 0);
        }
    }
    float b1v[4];
#pragma unroll
    for (int n = 0; n < 4; ++n) b1v[n] = b1[wv * 64 + n * 16 + lc];

    __syncthreads();   // all waves done reading pair tile
    // h = relu(acc + b1) -> bf16 back into LDS in A-frag order (k = hidden col)
#pragma unroll
    for (int m = 0; m < 4; ++m)
#pragma unroll
        for (int n = 0; n < 4; ++n) {
            const int hcol = wv * 64 + n * 16 + lc;
#pragma unroll
            for (int r = 0; r < 4; ++r) {
                const int row = m * 16 + lg * 4 + r;
                A_lds[stageOff(row, hcol)] = f2bf(fmaxf(acc[m][n][r] + b1v[n], 0.f));
            }
        }
    __syncthreads();

    // ---- layer 2 MFMA: (64 x 256) @ (256 x 128), wave owns 2 ntiles ----
    f32x4 acc2[4][2] = {};
    {
        const ushort* wbase = w2s + (size_t)(wv * 2) * 8 * 512;
#pragma unroll 2
        for (int t = 0; t < 8; ++t) {
            bf16x8 af[4], bfr[2];
#pragma unroll
            for (int m = 0; m < 4; ++m)
                af[m] = *(const bf16x8*)&A_lds[(m * 8 + t) * 512 + lane * 8];
#pragma unroll
            for (int n = 0; n < 2; ++n)
                bfr[n] = *(const bf16x8*)(wbase + (n * 8 + t) * 512 + lane * 8);
#pragma unroll
            for (int m = 0; m < 4; ++m)
#pragma unroll
                for (int n = 0; n < 2; ++n)
                    acc2[m][n] = __builtin_amdgcn_mfma_f32_16x16x32_bf16(af[m], bfr[n], acc2[m][n], 0, 0, 0);
        }
    }
    float b2v[2];
#pragma unroll
    for (int n = 0; n < 2; ++n) b2v[n] = b2[(wv * 2 + n) * 16 + lc];

#pragma unroll
    for (int m = 0; m < 4; ++m)
#pragma unroll
        for (int r = 0; r < 4; ++r) {
            const int row = m * 16 + lg * 4 + r;
            const int n = n0 + row;
            if (n >= NN) continue;
            const bool hit = lastL[row] > 0;
#pragma unroll
            for (int c = 0; c < 2; ++c) {
                const int col = (wv * 2 + c) * 16 + lc;
                const float ev = emb[(size_t)n * DD + col];
                outRes[(size_t)n * DD + col] =
                    hit ? (ev + acc2[m][c][r] + b2v[c]) * 0.5f : ev;
            }
        }
}

// ---------------------------------------------------------------------------
extern "C" void kernel_launch(void* const* d_in, const int* in_sizes, int n_in,
                              void* d_out, int out_size, void* d_ws, size_t ws_size,
                              hipStream_t stream)
{
    const float* emb = (const float*)d_in[0];
    const int*   edge = (const int*)d_in[1];
    const float* Wd1 = (const float*)d_in[2];
    const float* bd1 = (const float*)d_in[3];
    const float* Wd2 = (const float*)d_in[4];
    const float* bd2 = (const float*)d_in[5];
    const float* Wr1 = (const float*)d_in[6];
    const float* br1 = (const float*)d_in[7];
    const float* Wr2 = (const float*)d_in[8];
    const float* br2 = (const float*)d_in[9];

    const int* srcIdx = edge;
    const int* dstIdx = edge + EE;

    float* outRes = (float*)d_out;
    float* scores = outRes + (size_t)NN * DD;

    // ws layout: last[50000] (+pad) | flagCount | bf16 weights | flagList
    int* last = (int*)d_ws;
    int* flagCount = last + 50112;
    ushort* wd1s = (ushort*)(last + 50176);       // 65536 ushorts (128 KB)
    ushort* wr1s = wd1s + 65536;                  // 128 KB
    ushort* wr2s = wr1s + 65536;                  // 64 KB
    int* flagList = (int*)(wr2s + 32768);
    const size_t used = 50176 * 4 + (65536 + 65536 + 32768) * 2;
    long capL = ((long)ws_size - (long)used) / 4;
    int flagCap = (capL > 65536L) ? 65536 : (capL < 0 ? 0 : (int)capL);

    hipMemsetAsync(d_ws, 0, 50176 * sizeof(int), stream);   // last + flagCount

    swz_kernel<<<128, 64, 0, stream>>>(Wd1, wd1s, HH, 8);   // 256x256
    swz_kernel<<<128, 64, 0, stream>>>(Wr1, wr1s, HH, 8);   // 256x256
    swz_kernel<<<64, 64, 0, stream>>>(Wr2, wr2s, DD, 8);    // 256x128

    det_kernel<<<EE / TE, 256, 0, stream>>>(emb, srcIdx, dstIdx,
                                            wd1s, bd1, Wd2, bd2,
                                            scores, last, flagCount, flagList, flagCap);
    recheck_kernel<<<2048, 64, 0, stream>>>(emb, srcIdx, dstIdx,
                                            Wd1, bd1, Wd2, bd2,
                                            last, flagCount, flagList, flagCap);
    res_kernel<<<(NN + TE - 1) / TE, 256, 0, stream>>>(emb, srcIdx, dstIdx,
                                                       wr1s, br1, wr2s, br2,
                                                       last, outRes);
}

// Round 3
// 443.071 us; speedup vs baseline: 2.1762x; 1.5089x over previous
//
#include <hip/hip_runtime.h>
#include <math.h>

#define NN 50000      // nodes
#define DD 128        // embedding dim
#define K2D 256       // 2*D (pair width / GEMM K)
#define HH 256        // hidden
#define EE 400000     // edges
#define TE 64         // rows (edges or nodes) per block
#define TAU  0.02f    // |z_bf16| band -> fp32 refine (bf16 z err max ~2e-3)
#define TAU2 5e-5f    // |z_fp32| band -> fp64 decide (fp32 z err max ~2e-6)

typedef __attribute__((ext_vector_type(8))) short bf16x8;
typedef __attribute__((ext_vector_type(4))) float f32x4;
typedef unsigned int uint;
typedef unsigned short ushort;

__device__ __forceinline__ ushort f2bf(float x) {
    uint u = __builtin_bit_cast(uint, x);
    u = (u + 0x7FFFu + ((u >> 16) & 1u)) >> 16;   // RNE
    return (ushort)u;
}

// LDS A-tile in MFMA A-fragment order; see round-2 derivation.
__device__ __forceinline__ int stageOff(int r, int k) {
    return ((r >> 4) * 8 + (k >> 5)) * 512 + ((((k >> 3) & 3) << 4) + (r & 15)) * 8 + (k & 7);
}

// ---------------------------------------------------------------------------
// Weight swizzle: W (K x N fp32 row-major) -> bf16 MFMA B-frag order.
// ---------------------------------------------------------------------------
__global__ __launch_bounds__(64) void swz_kernel(const float* __restrict__ W,
                                                 ushort* __restrict__ out,
                                                 int N, int Kt)
{
    const int bid = blockIdx.x;
    const int n = bid / Kt, t = bid - n * Kt;
    const int l = threadIdx.x;
    const int row0 = t * 32 + (l >> 4) * 8;
    const int col = n * 16 + (l & 15);
    ushort tmp[8];
#pragma unroll
    for (int j = 0; j < 8; ++j) tmp[j] = f2bf(W[(row0 + j) * N + col]);
    uint4 p;
    p.x = (uint)tmp[0] | ((uint)tmp[1] << 16);
    p.y = (uint)tmp[2] | ((uint)tmp[3] << 16);
    p.z = (uint)tmp[4] | ((uint)tmp[5] << 16);
    p.w = (uint)tmp[6] | ((uint)tmp[7] << 16);
    *(uint4*)(out + ((size_t)bid * 64 + l) * 8) = p;
}

// ---------------------------------------------------------------------------
// Detector: z = relu(pair@Wd1+b1)@Wd2+b2 via bf16 MFMA; flag |z|<TAU.
// ---------------------------------------------------------------------------
__global__ __launch_bounds__(256) void det_kernel(
    const float* __restrict__ emb,
    const int* __restrict__ srcIdx, const int* __restrict__ dstIdx,
    const ushort* __restrict__ w1s, const float* __restrict__ b1,
    const float* __restrict__ W2, const float* __restrict__ b2p,
    float* __restrict__ scores,
    int* __restrict__ last,
    int* __restrict__ flagCount, int* __restrict__ flagList, int flagCap)
{
    __shared__ __align__(16) ushort A_lds[TE * K2D];   // 32 KB, frag order
    __shared__ float zp[256];
    const int tid = threadIdx.x;
    const int e0 = blockIdx.x * TE;

    {
        const int r = tid >> 2, q = tid & 3;
        const int e = e0 + r;
        const int node = (q < 2) ? srcIdx[e] : dstIdx[e];
        const float4* s4 = (const float4*)(emb + (size_t)node * DD + (q & 1) * 64);
#pragma unroll
        for (int u = 0; u < 16; ++u) {
            const float4 v = s4[u];
            const int k0 = q * 64 + u * 4;
            uint2 p;
            p.x = (uint)f2bf(v.x) | ((uint)f2bf(v.y) << 16);
            p.y = (uint)f2bf(v.z) | ((uint)f2bf(v.w) << 16);
            *(uint2*)&A_lds[stageOff(r, k0)] = p;
        }
    }
    __syncthreads();

    const int wv = tid >> 6;
    const int lane = tid & 63;
    const int lc = lane & 15, lg = lane >> 4;

    f32x4 acc[4][4] = {};
    const ushort* wbase = w1s + (size_t)(wv * 4) * 8 * 512;

#pragma unroll 2
    for (int t = 0; t < 8; ++t) {
        bf16x8 af[4], bfr[4];
#pragma unroll
        for (int m = 0; m < 4; ++m)
            af[m] = *(const bf16x8*)&A_lds[(m * 8 + t) * 512 + lane * 8];
#pragma unroll
        for (int n = 0; n < 4; ++n)
            bfr[n] = *(const bf16x8*)(wbase + (n * 8 + t) * 512 + lane * 8);
#pragma unroll
        for (int m = 0; m < 4; ++m)
#pragma unroll
            for (int n = 0; n < 4; ++n)
                acc[m][n] = __builtin_amdgcn_mfma_f32_16x16x32_bf16(af[m], bfr[n], acc[m][n], 0, 0, 0);
    }

    float b1v[4], w2v[4];
#pragma unroll
    for (int n = 0; n < 4; ++n) {
        const int col = wv * 64 + n * 16 + lc;
        b1v[n] = b1[col];
        w2v[n] = W2[col];
    }
    float pz[4][4];
#pragma unroll
    for (int m = 0; m < 4; ++m)
#pragma unroll
        for (int r = 0; r < 4; ++r) {
            float s = 0.f;
#pragma unroll
            for (int n = 0; n < 4; ++n)
                s = fmaf(fmaxf(acc[m][n][r] + b1v[n], 0.f), w2v[n], s);
            pz[m][r] = s;
        }
#pragma unroll
    for (int msk = 1; msk <= 8; msk <<= 1)
#pragma unroll
        for (int m = 0; m < 4; ++m)
#pragma unroll
            for (int r = 0; r < 4; ++r)
                pz[m][r] += __shfl_xor(pz[m][r], msk, 64);
    if (lc == 0) {
#pragma unroll
        for (int m = 0; m < 4; ++m)
#pragma unroll
            for (int r = 0; r < 4; ++r)
                zp[wv * 64 + m * 16 + lg * 4 + r] = pz[m][r];
    }
    __syncthreads();

    if (tid < 64) {
        const int e = e0 + tid;
        const float z = zp[tid] + zp[64 + tid] + zp[128 + tid] + zp[192 + tid] + *b2p;
        scores[e] = 1.0f / (1.0f + expf(-z));
        bool deferred = false;
        if (fabsf(z) < TAU) {
            const int slot = atomicAdd(flagCount, 1);
            if (slot < flagCap) { flagList[slot] = e; deferred = true; }
        }
        if (!deferred && z > 0.0f) {
            atomicMax(&last[srcIdx[e]], e + 1);
            atomicMax(&last[dstIdx[e]], e + 1);
        }
    }
}

// ---------------------------------------------------------------------------
// Stage B: fp32 refine of flagged edges. One 256-thr block per edge (j=tid),
// coalesced W1 column reads, 4 independent k-accumulators.
// ---------------------------------------------------------------------------
__global__ __launch_bounds__(256) void refine32_kernel(
    const float* __restrict__ emb,
    const int* __restrict__ srcIdx, const int* __restrict__ dstIdx,
    const float* __restrict__ W1, const float* __restrict__ b1,
    const float* __restrict__ W2, const float* __restrict__ b2p,
    int* __restrict__ last,
    const int* __restrict__ flagCount, const int* __restrict__ flagList, int flagCap,
    int* __restrict__ flagCount2, int* __restrict__ flagList2, int flagCap2)
{
    __shared__ float pair[K2D];
    __shared__ float wsum[4];
    const int tid = threadIdx.x;
    const int cnt = min(*flagCount, flagCap);
    for (int f = blockIdx.x; f < cnt; f += gridDim.x) {
        const int e = flagList[f];
        const int s = srcIdx[e], d = dstIdx[e];
        __syncthreads();
        pair[tid] = (tid < DD) ? emb[(size_t)s * DD + tid]
                               : emb[(size_t)d * DD + tid - DD];
        __syncthreads();
        float h0 = 0.f, h1 = 0.f, h2 = 0.f, h3 = 0.f;
        for (int k = 0; k < K2D; k += 4) {
            h0 = fmaf(pair[k],     W1[(k)     * HH + tid], h0);
            h1 = fmaf(pair[k + 1], W1[(k + 1) * HH + tid], h1);
            h2 = fmaf(pair[k + 2], W1[(k + 2) * HH + tid], h2);
            h3 = fmaf(pair[k + 3], W1[(k + 3) * HH + tid], h3);
        }
        const float h = b1[tid] + ((h0 + h1) + (h2 + h3));
        float v = fmaxf(h, 0.f) * W2[tid];
#pragma unroll
        for (int m = 1; m <= 32; m <<= 1) v += __shfl_xor(v, m, 64);
        if ((tid & 63) == 0) wsum[tid >> 6] = v;
        __syncthreads();
        if (tid == 0) {
            const float z = wsum[0] + wsum[1] + wsum[2] + wsum[3] + *b2p;
            if (fabsf(z) < TAU2) {
                const int slot = atomicAdd(flagCount2, 1);
                if (slot < flagCap2) {
                    flagList2[slot] = e;
                } else if (z > 0.f) {           // overflow fallback: fp32 sign
                    atomicMax(&last[s], e + 1);
                    atomicMax(&last[d], e + 1);
                }
            } else if (z > 0.f) {
                atomicMax(&last[s], e + 1);
                atomicMax(&last[d], e + 1);
            }
        }
        __syncthreads();
    }
}

// ---------------------------------------------------------------------------
// Stage C: fp64 final decision for the ~dozens of remaining edges (j=tid).
// ---------------------------------------------------------------------------
__global__ __launch_bounds__(256) void refine64_kernel(
    const float* __restrict__ emb,
    const int* __restrict__ srcIdx, const int* __restrict__ dstIdx,
    const float* __restrict__ W1, const float* __restrict__ b1,
    const float* __restrict__ W2, const float* __restrict__ b2p,
    int* __restrict__ last,
    const int* __restrict__ flagCount2, const int* __restrict__ flagList2,
    int flagCap2)
{
    __shared__ float pair[K2D];
    __shared__ double wsumd[4];
    const int tid = threadIdx.x;
    const int cnt = min(*flagCount2, flagCap2);
    for (int f = blockIdx.x; f < cnt; f += gridDim.x) {
        const int e = flagList2[f];
        const int s = srcIdx[e], d = dstIdx[e];
        __syncthreads();
        pair[tid] = (tid < DD) ? emb[(size_t)s * DD + tid]
                               : emb[(size_t)d * DD + tid - DD];
        __syncthreads();
        double h0 = 0.0, h1 = 0.0;
        for (int k = 0; k < K2D; k += 2) {
            h0 += (double)pair[k]     * (double)W1[(k)     * HH + tid];
            h1 += (double)pair[k + 1] * (double)W1[(k + 1) * HH + tid];
        }
        const double h = (double)b1[tid] + h0 + h1;
        double v = (h > 0.0) ? h * (double)W2[tid] : 0.0;
#pragma unroll
        for (int m = 1; m <= 32; m <<= 1) v += __shfl_xor(v, m, 64);
        if ((tid & 63) == 0) wsumd[tid >> 6] = v;
        __syncthreads();
        if (tid == 0) {
            const double z = wsumd[0] + wsumd[1] + wsumd[2] + wsumd[3] + (double)(*b2p);
            if (z > 0.0) {
                atomicMax(&last[s], e + 1);
                atomicMax(&last[d], e + 1);
            }
        }
        __syncthreads();
    }
}

// ---------------------------------------------------------------------------
// Resolver per NODE (winning edge only), both layers bf16 MFMA.
// ---------------------------------------------------------------------------
__global__ __launch_bounds__(256) void res_kernel(
    const float* __restrict__ emb,
    const int* __restrict__ srcIdx, const int* __restrict__ dstIdx,
    const ushort* __restrict__ w1s, const float* __restrict__ b1,
    const ushort* __restrict__ w2s, const float* __restrict__ b2,
    const int* __restrict__ last,
    float* __restrict__ outRes)
{
    __shared__ __align__(16) ushort A_lds[TE * K2D];
    __shared__ int lastL[TE];
    const int tid = threadIdx.x;
    const int n0 = blockIdx.x * TE;

    if (tid < TE) {
        const int n = n0 + tid;
        lastL[tid] = (n < NN) ? last[n] : 0;
    }
    {
        const int r = tid >> 2, q = tid & 3;
        const int n = n0 + r;
        int e = 0;
        if (n < NN) { const int l = last[n]; if (l > 0) e = l - 1; }
        const int node = (q < 2) ? srcIdx[e] : dstIdx[e];
        const float4* s4 = (const float4*)(emb + (size_t)node * DD + (q & 1) * 64);
#pragma unroll
        for (int u = 0; u < 16; ++u) {
            const float4 v = s4[u];
            const int k0 = q * 64 + u * 4;
            uint2 p;
            p.x = (uint)f2bf(v.x) | ((uint)f2bf(v.y) << 16);
            p.y = (uint)f2bf(v.z) | ((uint)f2bf(v.w) << 16);
            *(uint2*)&A_lds[stageOff(r, k0)] = p;
        }
    }
    __syncthreads();

    const int wv = tid >> 6;
    const int lane = tid & 63;
    const int lc = lane & 15, lg = lane >> 4;

    f32x4 acc[4][4] = {};
    {
        const ushort* wbase = w1s + (size_t)(wv * 4) * 8 * 512;
#pragma unroll 2
        for (int t = 0; t < 8; ++t) {
            bf16x8 af[4], bfr[4];
#pragma unroll
            for (int m = 0; m < 4; ++m)
                af[m] = *(const bf16x8*)&A_lds[(m * 8 + t) * 512 + lane * 8];
#pragma unroll
            for (int n = 0; n < 4; ++n)
                bfr[n] = *(const bf16x8*)(wbase + (n * 8 + t) * 512 + lane * 8);
#pragma unroll
            for (int m = 0; m < 4; ++m)
#pragma unroll
                for (int n = 0; n < 4; ++n)
                    acc[m][n] = __builtin_amdgcn_mfma_f32_16x16x32_bf16(af[m], bfr[n], acc[m][n], 0, 0, 0);
        }
    }
    float b1v[4];
#pragma unroll
    for (int n = 0; n < 4; ++n) b1v[n] = b1[wv * 64 + n * 16 + lc];

    __syncthreads();
#pragma unroll
    for (int m = 0; m < 4; ++m)
#pragma unroll
        for (int n = 0; n < 4; ++n) {
            const int hcol = wv * 64 + n * 16 + lc;
#pragma unroll
            for (int r = 0; r < 4; ++r) {
                const int row = m * 16 + lg * 4 + r;
                A_lds[stageOff(row, hcol)] = f2bf(fmaxf(acc[m][n][r] + b1v[n], 0.f));
            }
        }
    __syncthreads();

    f32x4 acc2[4][2] = {};
    {
        const ushort* wbase = w2s + (size_t)(wv * 2) * 8 * 512;
#pragma unroll 2
        for (int t = 0; t < 8; ++t) {
            bf16x8 af[4], bfr[2];
#pragma unroll
            for (int m = 0; m < 4; ++m)
                af[m] = *(const bf16x8*)&A_lds[(m * 8 + t) * 512 + lane * 8];
#pragma unroll
            for (int n = 0; n < 2; ++n)
                bfr[n] = *(const bf16x8*)(wbase + (n * 8 + t) * 512 + lane * 8);
#pragma unroll
            for (int m = 0; m < 4; ++m)
#pragma unroll
                for (int n = 0; n < 2; ++n)
                    acc2[m][n] = __builtin_amdgcn_mfma_f32_16x16x32_bf16(af[m], bfr[n], acc2[m][n], 0, 0, 0);
        }
    }
    float b2v[2];
#pragma unroll
    for (int n = 0; n < 2; ++n) b2v[n] = b2[(wv * 2 + n) * 16 + lc];

#pragma unroll
    for (int m = 0; m < 4; ++m)
#pragma unroll
        for (int r = 0; r < 4; ++r) {
            const int row = m * 16 + lg * 4 + r;
            const int n = n0 + row;
            if (n >= NN) continue;
            const bool hit = lastL[row] > 0;
#pragma unroll
            for (int c = 0; c < 2; ++c) {
                const int col = (wv * 2 + c) * 16 + lc;
                const float ev = emb[(size_t)n * DD + col];
                outRes[(size_t)n * DD + col] =
                    hit ? (ev + acc2[m][c][r] + b2v[c]) * 0.5f : ev;
            }
        }
}

// ---------------------------------------------------------------------------
extern "C" void kernel_launch(void* const* d_in, const int* in_sizes, int n_in,
                              void* d_out, int out_size, void* d_ws, size_t ws_size,
                              hipStream_t stream)
{
    const float* emb = (const float*)d_in[0];
    const int*   edge = (const int*)d_in[1];
    const float* Wd1 = (const float*)d_in[2];
    const float* bd1 = (const float*)d_in[3];
    const float* Wd2 = (const float*)d_in[4];
    const float* bd2 = (const float*)d_in[5];
    const float* Wr1 = (const float*)d_in[6];
    const float* br1 = (const float*)d_in[7];
    const float* Wr2 = (const float*)d_in[8];
    const float* br2 = (const float*)d_in[9];

    const int* srcIdx = edge;
    const int* dstIdx = edge + EE;

    float* outRes = (float*)d_out;
    float* scores = outRes + (size_t)NN * DD;

    // ws layout: last[50000+pad] | flagCount | flagCount2 | bf16 weights |
    //            flagList[65536] | flagList2[8192]
    int* last = (int*)d_ws;
    int* flagCount  = last + 50112;
    int* flagCount2 = last + 50113;
    ushort* wd1s = (ushort*)(last + 50176);       // 128 KB
    ushort* wr1s = wd1s + 65536;                  // 128 KB
    ushort* wr2s = wr1s + 65536;                  // 64 KB
    int* flagList  = (int*)(wr2s + 32768);
    int* flagList2 = flagList + 65536;
    const size_t used = 50176 * 4 + (65536 + 65536 + 32768) * 2 + 65536 * 4 + 8192 * 4;
    long capL = ((long)ws_size - (long)(used - 65536 * 4 - 8192 * 4)) / 4;
    int flagCap  = 65536;
    int flagCap2 = 8192;
    if (capL < 65536 + 8192) {   // degenerate small-ws guard
        flagCap  = capL > 8192 ? (int)(capL - 8192) : 0;
        flagCap2 = capL > 8192 ? 8192 : (capL < 0 ? 0 : (int)capL);
    }

    hipMemsetAsync(d_ws, 0, 50176 * sizeof(int), stream);   // last + both counters

    swz_kernel<<<128, 64, 0, stream>>>(Wd1, wd1s, HH, 8);
    swz_kernel<<<128, 64, 0, stream>>>(Wr1, wr1s, HH, 8);
    swz_kernel<<<64, 64, 0, stream>>>(Wr2, wr2s, DD, 8);

    det_kernel<<<EE / TE, 256, 0, stream>>>(emb, srcIdx, dstIdx,
                                            wd1s, bd1, Wd2, bd2,
                                            scores, last, flagCount, flagList, flagCap);
    refine32_kernel<<<4096, 256, 0, stream>>>(emb, srcIdx, dstIdx,
                                              Wd1, bd1, Wd2, bd2,
                                              last, flagCount, flagList, flagCap,
                                              flagCount2, flagList2, flagCap2);
    refine64_kernel<<<512, 256, 0, stream>>>(emb, srcIdx, dstIdx,
                                             Wd1, bd1, Wd2, bd2,
                                             last, flagCount2, flagList2, flagCap2);
    res_kernel<<<(NN + TE - 1) / TE, 256, 0, stream>>>(emb, srcIdx, dstIdx,
                                                       wr1s, br1, wr2s, br2,
                                                       last, outRes);
}

// Round 4
// 257.219 us; speedup vs baseline: 3.7485x; 1.7225x over previous
//
#include <hip/hip_runtime.h>
#include <math.h>

#define NN 50000      // nodes
#define DD 128        // embedding dim
#define K2D 256       // 2*D (pair width / GEMM K)
#define HH 256        // hidden
#define EE 400000     // edges
#define TE 64         // rows (edges or nodes) per block
#define RT 64         // flagged edges per refine tile
#define PST 260       // padded fp32 LDS row stride
#define TAU  0.02f    // |z_bf16| band -> fp32 refine (bf16 z err max ~2e-3)
#define TAU2 5e-5f    // |z_fp32| band -> fp64 decide (fp32 z err max ~1.5e-5)

typedef __attribute__((ext_vector_type(8))) short bf16x8;
typedef __attribute__((ext_vector_type(4))) float f32x4;
typedef unsigned int uint;
typedef unsigned short ushort;

__device__ __forceinline__ ushort f2bf(float x) {
    uint u = __builtin_bit_cast(uint, x);
    u = (u + 0x7FFFu + ((u >> 16) & 1u)) >> 16;   // RNE
    return (ushort)u;
}

// LDS A-tile in MFMA A-fragment order; see round-2 derivation.
__device__ __forceinline__ int stageOff(int r, int k) {
    return ((r >> 4) * 8 + (k >> 5)) * 512 + ((((k >> 3) & 3) << 4) + (r & 15)) * 8 + (k & 7);
}

// ---------------------------------------------------------------------------
// Weight swizzle: W (K x N fp32 row-major) -> bf16 MFMA B-frag order.
// ---------------------------------------------------------------------------
__global__ __launch_bounds__(64) void swz_kernel(const float* __restrict__ W,
                                                 ushort* __restrict__ out,
                                                 int N, int Kt)
{
    const int bid = blockIdx.x;
    const int n = bid / Kt, t = bid - n * Kt;
    const int l = threadIdx.x;
    const int row0 = t * 32 + (l >> 4) * 8;
    const int col = n * 16 + (l & 15);
    ushort tmp[8];
#pragma unroll
    for (int j = 0; j < 8; ++j) tmp[j] = f2bf(W[(row0 + j) * N + col]);
    uint4 p;
    p.x = (uint)tmp[0] | ((uint)tmp[1] << 16);
    p.y = (uint)tmp[2] | ((uint)tmp[3] << 16);
    p.z = (uint)tmp[4] | ((uint)tmp[5] << 16);
    p.w = (uint)tmp[6] | ((uint)tmp[7] << 16);
    *(uint4*)(out + ((size_t)bid * 64 + l) * 8) = p;
}

// ---------------------------------------------------------------------------
// Detector: z = relu(pair@Wd1+b1)@Wd2+b2 via bf16 MFMA; flag |z|<TAU.
// ---------------------------------------------------------------------------
__global__ __launch_bounds__(256) void det_kernel(
    const float* __restrict__ emb,
    const int* __restrict__ srcIdx, const int* __restrict__ dstIdx,
    const ushort* __restrict__ w1s, const float* __restrict__ b1,
    const float* __restrict__ W2, const float* __restrict__ b2p,
    float* __restrict__ scores,
    int* __restrict__ last,
    int* __restrict__ flagCount, int* __restrict__ flagList, int flagCap)
{
    __shared__ __align__(16) ushort A_lds[TE * K2D];   // 32 KB, frag order
    __shared__ float zp[256];
    const int tid = threadIdx.x;
    const int e0 = blockIdx.x * TE;

    {
        const int r = tid >> 2, q = tid & 3;
        const int e = e0 + r;
        const int node = (q < 2) ? srcIdx[e] : dstIdx[e];
        const float4* s4 = (const float4*)(emb + (size_t)node * DD + (q & 1) * 64);
#pragma unroll
        for (int u = 0; u < 16; ++u) {
            const float4 v = s4[u];
            const int k0 = q * 64 + u * 4;
            uint2 p;
            p.x = (uint)f2bf(v.x) | ((uint)f2bf(v.y) << 16);
            p.y = (uint)f2bf(v.z) | ((uint)f2bf(v.w) << 16);
            *(uint2*)&A_lds[stageOff(r, k0)] = p;
        }
    }
    __syncthreads();

    const int wv = tid >> 6;
    const int lane = tid & 63;
    const int lc = lane & 15, lg = lane >> 4;

    f32x4 acc[4][4] = {};
    const ushort* wbase = w1s + (size_t)(wv * 4) * 8 * 512;

#pragma unroll 2
    for (int t = 0; t < 8; ++t) {
        bf16x8 af[4], bfr[4];
#pragma unroll
        for (int m = 0; m < 4; ++m)
            af[m] = *(const bf16x8*)&A_lds[(m * 8 + t) * 512 + lane * 8];
#pragma unroll
        for (int n = 0; n < 4; ++n)
            bfr[n] = *(const bf16x8*)(wbase + (n * 8 + t) * 512 + lane * 8);
#pragma unroll
        for (int m = 0; m < 4; ++m)
#pragma unroll
            for (int n = 0; n < 4; ++n)
                acc[m][n] = __builtin_amdgcn_mfma_f32_16x16x32_bf16(af[m], bfr[n], acc[m][n], 0, 0, 0);
    }

    float b1v[4], w2v[4];
#pragma unroll
    for (int n = 0; n < 4; ++n) {
        const int col = wv * 64 + n * 16 + lc;
        b1v[n] = b1[col];
        w2v[n] = W2[col];
    }
    float pz[4][4];
#pragma unroll
    for (int m = 0; m < 4; ++m)
#pragma unroll
        for (int r = 0; r < 4; ++r) {
            float s = 0.f;
#pragma unroll
            for (int n = 0; n < 4; ++n)
                s = fmaf(fmaxf(acc[m][n][r] + b1v[n], 0.f), w2v[n], s);
            pz[m][r] = s;
        }
#pragma unroll
    for (int msk = 1; msk <= 8; msk <<= 1)
#pragma unroll
        for (int m = 0; m < 4; ++m)
#pragma unroll
            for (int r = 0; r < 4; ++r)
                pz[m][r] += __shfl_xor(pz[m][r], msk, 64);
    if (lc == 0) {
#pragma unroll
        for (int m = 0; m < 4; ++m)
#pragma unroll
            for (int r = 0; r < 4; ++r)
                zp[wv * 64 + m * 16 + lg * 4 + r] = pz[m][r];
    }
    __syncthreads();

    if (tid < 64) {
        const int e = e0 + tid;
        const float z = zp[tid] + zp[64 + tid] + zp[128 + tid] + zp[192 + tid] + *b2p;
        scores[e] = 1.0f / (1.0f + expf(-z));
        bool deferred = false;
        if (fabsf(z) < TAU) {
            const int slot = atomicAdd(flagCount, 1);
            if (slot < flagCap) { flagList[slot] = e; deferred = true; }
        }
        if (!deferred && z > 0.0f) {
            atomicMax(&last[srcIdx[e]], e + 1);
            atomicMax(&last[dstIdx[e]], e + 1);
        }
    }
}

// ---------------------------------------------------------------------------
// Stage B: fp32 refine, TILED. 64 flagged edges per block tile so W1 is read
// once per tile (not once per edge). Round-1 micro-tile GEMM structure.
// ---------------------------------------------------------------------------
__global__ __launch_bounds__(256) void refine32_kernel(
    const float* __restrict__ emb,
    const int* __restrict__ srcIdx, const int* __restrict__ dstIdx,
    const float* __restrict__ W1, const float* __restrict__ b1,
    const float* __restrict__ W2, const float* __restrict__ b2p,
    int* __restrict__ last,
    const int* __restrict__ flagCount, const int* __restrict__ flagList, int flagCap,
    int* __restrict__ flagCount2, int* __restrict__ flagList2, int flagCap2)
{
    __shared__ __align__(16) float P[RT * PST];
    __shared__ int eL[RT];
    const int tid = threadIdx.x;
    const int cnt = min(*flagCount, flagCap);
    const int nTiles = (cnt + RT - 1) / RT;
    const float b2v = *b2p;

    for (int T = blockIdx.x; T < nTiles; T += gridDim.x) {
        if (tid < RT) {
            const int idx = T * RT + tid;
            eL[tid] = flagList[min(idx, cnt - 1)];
        }
        __syncthreads();
        {
            const int i = tid >> 2, q = tid & 3;
            const int e = eL[i];
            const int node = (q < 2) ? srcIdx[e] : dstIdx[e];
            const float4* s4 = (const float4*)(emb + (size_t)node * DD + (q & 1) * 64);
            float4* d4 = (float4*)(P + i * PST + q * 64);
#pragma unroll
            for (int t = 0; t < 16; ++t) d4[t] = s4[t];
        }
        __syncthreads();

        const int rowg = tid >> 5;
        const int colg = tid & 31;
        const int c0 = colg * 8;

        float acc[8][8];
#pragma unroll
        for (int c = 0; c < 8; ++c) {
            const float bv = b1[c0 + c];
#pragma unroll
            for (int r = 0; r < 8; ++r) acc[r][c] = bv;
        }
        for (int kk = 0; kk < K2D; kk += 4) {
            float af[8][4];
#pragma unroll
            for (int r = 0; r < 8; ++r) {
                const float4 v = *(const float4*)&P[(rowg * 8 + r) * PST + kk];
                af[r][0] = v.x; af[r][1] = v.y; af[r][2] = v.z; af[r][3] = v.w;
            }
#pragma unroll
            for (int dk = 0; dk < 4; ++dk) {
                const float4 w0 = *(const float4*)&W1[(kk + dk) * HH + c0];
                const float4 w1 = *(const float4*)&W1[(kk + dk) * HH + c0 + 4];
#pragma unroll
                for (int r = 0; r < 8; ++r) {
                    const float av = af[r][dk];
                    acc[r][0] = fmaf(av, w0.x, acc[r][0]);
                    acc[r][1] = fmaf(av, w0.y, acc[r][1]);
                    acc[r][2] = fmaf(av, w0.z, acc[r][2]);
                    acc[r][3] = fmaf(av, w0.w, acc[r][3]);
                    acc[r][4] = fmaf(av, w1.x, acc[r][4]);
                    acc[r][5] = fmaf(av, w1.y, acc[r][5]);
                    acc[r][6] = fmaf(av, w1.z, acc[r][6]);
                    acc[r][7] = fmaf(av, w1.w, acc[r][7]);
                }
            }
        }

        float w2[8];
#pragma unroll
        for (int c = 0; c < 8; ++c) w2[c] = W2[c0 + c];
        float pz[8];
#pragma unroll
        for (int r = 0; r < 8; ++r) {
            float s = 0.f;
#pragma unroll
            for (int c = 0; c < 8; ++c) s = fmaf(fmaxf(acc[r][c], 0.f), w2[c], s);
            pz[r] = s;
        }
#pragma unroll
        for (int m = 1; m <= 16; m <<= 1) {
#pragma unroll
            for (int r = 0; r < 8; ++r) pz[r] += __shfl_xor(pz[r], m, 64);
        }

        if (colg == 0) {
            for (int r = 0; r < 8; ++r) {
                const int row = rowg * 8 + r;
                const int idx = T * RT + row;
                if (idx < cnt) {
                    const int e = eL[row];
                    const int s = srcIdx[e], d = dstIdx[e];
                    const float z = pz[r] + b2v;
                    if (fabsf(z) < TAU2) {
                        const int slot = atomicAdd(flagCount2, 1);
                        if (slot < flagCap2) {
                            flagList2[slot] = e;
                        } else if (z > 0.f) {   // overflow fallback: fp32 sign
                            atomicMax(&last[s], e + 1);
                            atomicMax(&last[d], e + 1);
                        }
                    } else if (z > 0.f) {
                        atomicMax(&last[s], e + 1);
                        atomicMax(&last[d], e + 1);
                    }
                }
            }
        }
        __syncthreads();   // protect P/eL before next tile's overwrite
    }
}

// ---------------------------------------------------------------------------
// Stage C: fp64 final decision for the ~dozens of remaining edges (j=tid).
// ---------------------------------------------------------------------------
__global__ __launch_bounds__(256) void refine64_kernel(
    const float* __restrict__ emb,
    const int* __restrict__ srcIdx, const int* __restrict__ dstIdx,
    const float* __restrict__ W1, const float* __restrict__ b1,
    const float* __restrict__ W2, const float* __restrict__ b2p,
    int* __restrict__ last,
    const int* __restrict__ flagCount2, const int* __restrict__ flagList2,
    int flagCap2)
{
    __shared__ float pair[K2D];
    __shared__ double wsumd[4];
    const int tid = threadIdx.x;
    const int cnt = min(*flagCount2, flagCap2);
    for (int f = blockIdx.x; f < cnt; f += gridDim.x) {
        const int e = flagList2[f];
        const int s = srcIdx[e], d = dstIdx[e];
        __syncthreads();
        pair[tid] = (tid < DD) ? emb[(size_t)s * DD + tid]
                               : emb[(size_t)d * DD + tid - DD];
        __syncthreads();
        double h0 = 0.0, h1 = 0.0;
        for (int k = 0; k < K2D; k += 2) {
            h0 += (double)pair[k]     * (double)W1[(k)     * HH + tid];
            h1 += (double)pair[k + 1] * (double)W1[(k + 1) * HH + tid];
        }
        const double h = (double)b1[tid] + h0 + h1;
        double v = (h > 0.0) ? h * (double)W2[tid] : 0.0;
#pragma unroll
        for (int m = 1; m <= 32; m <<= 1) v += __shfl_xor(v, m, 64);
        if ((tid & 63) == 0) wsumd[tid >> 6] = v;
        __syncthreads();
        if (tid == 0) {
            const double z = wsumd[0] + wsumd[1] + wsumd[2] + wsumd[3] + (double)(*b2p);
            if (z > 0.0) {
                atomicMax(&last[s], e + 1);
                atomicMax(&last[d], e + 1);
            }
        }
        __syncthreads();
    }
}

// ---------------------------------------------------------------------------
// Resolver per NODE (winning edge only), both layers bf16 MFMA.
// ---------------------------------------------------------------------------
__global__ __launch_bounds__(256) void res_kernel(
    const float* __restrict__ emb,
    const int* __restrict__ srcIdx, const int* __restrict__ dstIdx,
    const ushort* __restrict__ w1s, const float* __restrict__ b1,
    const ushort* __restrict__ w2s, const float* __restrict__ b2,
    const int* __restrict__ last,
    float* __restrict__ outRes)
{
    __shared__ __align__(16) ushort A_lds[TE * K2D];
    __shared__ int lastL[TE];
    const int tid = threadIdx.x;
    const int n0 = blockIdx.x * TE;

    if (tid < TE) {
        const int n = n0 + tid;
        lastL[tid] = (n < NN) ? last[n] : 0;
    }
    {
        const int r = tid >> 2, q = tid & 3;
        const int n = n0 + r;
        int e = 0;
        if (n < NN) { const int l = last[n]; if (l > 0) e = l - 1; }
        const int node = (q < 2) ? srcIdx[e] : dstIdx[e];
        const float4* s4 = (const float4*)(emb + (size_t)node * DD + (q & 1) * 64);
#pragma unroll
        for (int u = 0; u < 16; ++u) {
            const float4 v = s4[u];
            const int k0 = q * 64 + u * 4;
            uint2 p;
            p.x = (uint)f2bf(v.x) | ((uint)f2bf(v.y) << 16);
            p.y = (uint)f2bf(v.z) | ((uint)f2bf(v.w) << 16);
            *(uint2*)&A_lds[stageOff(r, k0)] = p;
        }
    }
    __syncthreads();

    const int wv = tid >> 6;
    const int lane = tid & 63;
    const int lc = lane & 15, lg = lane >> 4;

    f32x4 acc[4][4] = {};
    {
        const ushort* wbase = w1s + (size_t)(wv * 4) * 8 * 512;
#pragma unroll 2
        for (int t = 0; t < 8; ++t) {
            bf16x8 af[4], bfr[4];
#pragma unroll
            for (int m = 0; m < 4; ++m)
                af[m] = *(const bf16x8*)&A_lds[(m * 8 + t) * 512 + lane * 8];
#pragma unroll
            for (int n = 0; n < 4; ++n)
                bfr[n] = *(const bf16x8*)(wbase + (n * 8 + t) * 512 + lane * 8);
#pragma unroll
            for (int m = 0; m < 4; ++m)
#pragma unroll
                for (int n = 0; n < 4; ++n)
                    acc[m][n] = __builtin_amdgcn_mfma_f32_16x16x32_bf16(af[m], bfr[n], acc[m][n], 0, 0, 0);
        }
    }
    float b1v[4];
#pragma unroll
    for (int n = 0; n < 4; ++n) b1v[n] = b1[wv * 64 + n * 16 + lc];

    __syncthreads();
#pragma unroll
    for (int m = 0; m < 4; ++m)
#pragma unroll
        for (int n = 0; n < 4; ++n) {
            const int hcol = wv * 64 + n * 16 + lc;
#pragma unroll
            for (int r = 0; r < 4; ++r) {
                const int row = m * 16 + lg * 4 + r;
                A_lds[stageOff(row, hcol)] = f2bf(fmaxf(acc[m][n][r] + b1v[n], 0.f));
            }
        }
    __syncthreads();

    f32x4 acc2[4][2] = {};
    {
        const ushort* wbase = w2s + (size_t)(wv * 2) * 8 * 512;
#pragma unroll 2
        for (int t = 0; t < 8; ++t) {
            bf16x8 af[4], bfr[2];
#pragma unroll
            for (int m = 0; m < 4; ++m)
                af[m] = *(const bf16x8*)&A_lds[(m * 8 + t) * 512 + lane * 8];
#pragma unroll
            for (int n = 0; n < 2; ++n)
                bfr[n] = *(const bf16x8*)(wbase + (n * 8 + t) * 512 + lane * 8);
#pragma unroll
            for (int m = 0; m < 4; ++m)
#pragma unroll
                for (int n = 0; n < 2; ++n)
                    acc2[m][n] = __builtin_amdgcn_mfma_f32_16x16x32_bf16(af[m], bfr[n], acc2[m][n], 0, 0, 0);
        }
    }
    float b2v[2];
#pragma unroll
    for (int n = 0; n < 2; ++n) b2v[n] = b2[(wv * 2 + n) * 16 + lc];

#pragma unroll
    for (int m = 0; m < 4; ++m)
#pragma unroll
        for (int r = 0; r < 4; ++r) {
            const int row = m * 16 + lg * 4 + r;
            const int n = n0 + row;
            if (n >= NN) continue;
            const bool hit = lastL[row] > 0;
#pragma unroll
            for (int c = 0; c < 2; ++c) {
                const int col = (wv * 2 + c) * 16 + lc;
                const float ev = emb[(size_t)n * DD + col];
                outRes[(size_t)n * DD + col] =
                    hit ? (ev + acc2[m][c][r] + b2v[c]) * 0.5f : ev;
            }
        }
}

// ---------------------------------------------------------------------------
extern "C" void kernel_launch(void* const* d_in, const int* in_sizes, int n_in,
                              void* d_out, int out_size, void* d_ws, size_t ws_size,
                              hipStream_t stream)
{
    const float* emb = (const float*)d_in[0];
    const int*   edge = (const int*)d_in[1];
    const float* Wd1 = (const float*)d_in[2];
    const float* bd1 = (const float*)d_in[3];
    const float* Wd2 = (const float*)d_in[4];
    const float* bd2 = (const float*)d_in[5];
    const float* Wr1 = (const float*)d_in[6];
    const float* br1 = (const float*)d_in[7];
    const float* Wr2 = (const float*)d_in[8];
    const float* br2 = (const float*)d_in[9];

    const int* srcIdx = edge;
    const int* dstIdx = edge + EE;

    float* outRes = (float*)d_out;
    float* scores = outRes + (size_t)NN * DD;

    // ws layout: last[50000+pad] | flagCount | flagCount2 | bf16 weights |
    //            flagList[65536] | flagList2[8192]
    int* last = (int*)d_ws;
    int* flagCount  = last + 50112;
    int* flagCount2 = last + 50113;
    ushort* wd1s = (ushort*)(last + 50176);       // 128 KB
    ushort* wr1s = wd1s + 65536;                  // 128 KB
    ushort* wr2s = wr1s + 65536;                  // 64 KB
    int* flagList  = (int*)(wr2s + 32768);
    int* flagList2 = flagList + 65536;
    long wsInts = (long)(ws_size / 4);
    long avail = wsInts - (50176 + (65536 + 65536 + 32768) / 2);
    int flagCap  = 65536;
    int flagCap2 = 8192;
    if (avail < 65536 + 8192) {   // degenerate small-ws guard
        flagCap  = avail > 8192 ? (int)(avail - 8192) : 0;
        flagCap2 = avail > 8192 ? 8192 : (avail < 0 ? 0 : (int)avail);
    }

    hipMemsetAsync(d_ws, 0, 50176 * sizeof(int), stream);   // last + both counters

    swz_kernel<<<128, 64, 0, stream>>>(Wd1, wd1s, HH, 8);
    swz_kernel<<<128, 64, 0, stream>>>(Wr1, wr1s, HH, 8);
    swz_kernel<<<64, 64, 0, stream>>>(Wr2, wr2s, DD, 8);

    det_kernel<<<EE / TE, 256, 0, stream>>>(emb, srcIdx, dstIdx,
                                            wd1s, bd1, Wd2, bd2,
                                            scores, last, flagCount, flagList, flagCap);
    refine32_kernel<<<512, 256, 0, stream>>>(emb, srcIdx, dstIdx,
                                             Wd1, bd1, Wd2, bd2,
                                             last, flagCount, flagList, flagCap,
                                             flagCount2, flagList2, flagCap2);
    refine64_kernel<<<512, 256, 0, stream>>>(emb, srcIdx, dstIdx,
                                             Wd1, bd1, Wd2, bd2,
                                             last, flagCount2, flagList2, flagCap2);
    res_kernel<<<(NN + TE - 1) / TE, 256, 0, stream>>>(emb, srcIdx, dstIdx,
                                                       wr1s, br1, wr2s, br2,
                                                       last, outRes);
}

// Round 5
// 255.792 us; speedup vs baseline: 3.7695x; 1.0056x over previous
//
#include <hip/hip_runtime.h>
#include <math.h>

#define NN 50000      // nodes
#define DD 128        // embedding dim
#define K2D 256       // 2*D (pair width / GEMM K)
#define HH 256        // hidden
#define EE 400000     // edges
#define TE 64         // rows (edges or nodes) per block
#define RT 64         // flagged edges per refine tile
#define PST 260       // padded fp32 LDS row stride
#define TAU  0.02f    // |z_bf16| band -> fp32 refine (bf16 z err max ~2e-3)
#define TAU2 5e-5f    // |z_fp32| band -> fp64 decide (fp32 z err max ~1.5e-5)

typedef __attribute__((ext_vector_type(8))) short bf16x8;
typedef __attribute__((ext_vector_type(4))) float f32x4;
typedef unsigned int uint;
typedef unsigned short ushort;

typedef __attribute__((address_space(3))) void lds_void_t;
typedef __attribute__((address_space(1))) void g1_void_t;

__device__ __forceinline__ ushort f2bf(float x) {
    uint u = __builtin_bit_cast(uint, x);
    u = (u + 0x7FFFu + ((u >> 16) & 1u)) >> 16;   // RNE
    return (ushort)u;
}

// LDS A-tile in MFMA A-fragment order (round-2 derivation):
// (r,k) -> sid=(r>>4)*8+(k>>5), lane=((k>>3)&3)*16+(r&15), j=k&7
__device__ __forceinline__ int stageOff(int r, int k) {
    return ((r >> 4) * 8 + (k >> 5)) * 512 + ((((k >> 3) & 3) << 4) + (r & 15)) * 8 + (k & 7);
}

// ---------------------------------------------------------------------------
// emb fp32 -> bf16 (one pass; bit-identical to in-kernel f2bf staging)
// ---------------------------------------------------------------------------
__global__ __launch_bounds__(256) void conv_kernel(const float* __restrict__ emb,
                                                   ushort* __restrict__ out)
{
    const int i = blockIdx.x * 256 + threadIdx.x;   // one 8-float chunk each
    if (i >= NN * DD / 8) return;
    const float4 a = ((const float4*)emb)[(size_t)i * 2];
    const float4 b = ((const float4*)emb)[(size_t)i * 2 + 1];
    uint4 p;
    p.x = (uint)f2bf(a.x) | ((uint)f2bf(a.y) << 16);
    p.y = (uint)f2bf(a.z) | ((uint)f2bf(a.w) << 16);
    p.z = (uint)f2bf(b.x) | ((uint)f2bf(b.y) << 16);
    p.w = (uint)f2bf(b.z) | ((uint)f2bf(b.w) << 16);
    *(uint4*)(out + (size_t)i * 8) = p;
}

// ---------------------------------------------------------------------------
// Weight swizzle: W (K x N fp32 row-major) -> bf16 MFMA B-frag order.
// ---------------------------------------------------------------------------
__global__ __launch_bounds__(64) void swz_kernel(const float* __restrict__ W,
                                                 ushort* __restrict__ out,
                                                 int N, int Kt)
{
    const int bid = blockIdx.x;
    const int n = bid / Kt, t = bid - n * Kt;
    const int l = threadIdx.x;
    const int row0 = t * 32 + (l >> 4) * 8;
    const int col = n * 16 + (l & 15);
    ushort tmp[8];
#pragma unroll
    for (int j = 0; j < 8; ++j) tmp[j] = f2bf(W[(row0 + j) * N + col]);
    uint4 p;
    p.x = (uint)tmp[0] | ((uint)tmp[1] << 16);
    p.y = (uint)tmp[2] | ((uint)tmp[3] << 16);
    p.z = (uint)tmp[4] | ((uint)tmp[5] << 16);
    p.w = (uint)tmp[6] | ((uint)tmp[7] << 16);
    *(uint4*)(out + ((size_t)bid * 64 + l) * 8) = p;
}

// ---------------------------------------------------------------------------
// Detector: z = relu(pair@Wd1+b1)@Wd2+b2 via bf16 MFMA; flag |z|<TAU.
// BF=1: DMA-stage bf16 emb straight into frag-order LDS (global_load_lds x8).
// ---------------------------------------------------------------------------
template<int BF>
__global__ __launch_bounds__(256) void det_kernel(
    const float* __restrict__ emb, const ushort* __restrict__ embbf,
    const int* __restrict__ srcIdx, const int* __restrict__ dstIdx,
    const ushort* __restrict__ w1s, const float* __restrict__ b1,
    const float* __restrict__ W2, const float* __restrict__ b2p,
    float* __restrict__ scores,
    int* __restrict__ last,
    int* __restrict__ flagCount, int* __restrict__ flagList, int flagCap)
{
    __shared__ __align__(16) ushort A_lds[TE * K2D];   // 32 KB, frag order
    __shared__ float zp[256];
    const int tid = threadIdx.x;
    const int e0 = blockIdx.x * TE;
    const int wv = tid >> 6;
    const int lane = tid & 63;

    if (BF) {
        // wave wv owns m-tile wv: rows wv*16 + (lane&15)
        const int r = wv * 16 + (lane & 15);
        const int e = e0 + r;
        const int ns = srcIdx[e], nd = dstIdx[e];
        const int ko = (lane >> 4) * 8;
#pragma unroll
        for (int s = 0; s < 8; ++s) {
            const int node = (s < 4) ? ns : nd;
            const ushort* g = embbf + (size_t)node * DD + (s & 3) * 32 + ko;
            __builtin_amdgcn_global_load_lds((const g1_void_t*)g,
                                             (lds_void_t*)&A_lds[(wv * 8 + s) * 512],
                                             16, 0, 0);
        }
    } else {
        const int r = tid >> 2, q = tid & 3;
        const int e = e0 + r;
        const int node = (q < 2) ? srcIdx[e] : dstIdx[e];
        const float4* s4 = (const float4*)(emb + (size_t)node * DD + (q & 1) * 64);
#pragma unroll
        for (int u = 0; u < 16; ++u) {
            const float4 v = s4[u];
            const int k0 = q * 64 + u * 4;
            uint2 p;
            p.x = (uint)f2bf(v.x) | ((uint)f2bf(v.y) << 16);
            p.y = (uint)f2bf(v.z) | ((uint)f2bf(v.w) << 16);
            *(uint2*)&A_lds[stageOff(r, k0)] = p;
        }
    }
    __syncthreads();

    const int lc = lane & 15, lg = lane >> 4;

    f32x4 acc[4][4] = {};
    const ushort* wbase = w1s + (size_t)(wv * 4) * 8 * 512;

#pragma unroll 2
    for (int t = 0; t < 8; ++t) {
        bf16x8 af[4], bfr[4];
#pragma unroll
        for (int m = 0; m < 4; ++m)
            af[m] = *(const bf16x8*)&A_lds[(m * 8 + t) * 512 + lane * 8];
#pragma unroll
        for (int n = 0; n < 4; ++n)
            bfr[n] = *(const bf16x8*)(wbase + (n * 8 + t) * 512 + lane * 8);
#pragma unroll
        for (int m = 0; m < 4; ++m)
#pragma unroll
            for (int n = 0; n < 4; ++n)
                acc[m][n] = __builtin_amdgcn_mfma_f32_16x16x32_bf16(af[m], bfr[n], acc[m][n], 0, 0, 0);
    }

    float b1v[4], w2v[4];
#pragma unroll
    for (int n = 0; n < 4; ++n) {
        const int col = wv * 64 + n * 16 + lc;
        b1v[n] = b1[col];
        w2v[n] = W2[col];
    }
    float pz[4][4];
#pragma unroll
    for (int m = 0; m < 4; ++m)
#pragma unroll
        for (int r = 0; r < 4; ++r) {
            float s = 0.f;
#pragma unroll
            for (int n = 0; n < 4; ++n)
                s = fmaf(fmaxf(acc[m][n][r] + b1v[n], 0.f), w2v[n], s);
            pz[m][r] = s;
        }
#pragma unroll
    for (int msk = 1; msk <= 8; msk <<= 1)
#pragma unroll
        for (int m = 0; m < 4; ++m)
#pragma unroll
            for (int r = 0; r < 4; ++r)
                pz[m][r] += __shfl_xor(pz[m][r], msk, 64);
    if (lc == 0) {
#pragma unroll
        for (int m = 0; m < 4; ++m)
#pragma unroll
            for (int r = 0; r < 4; ++r)
                zp[wv * 64 + m * 16 + lg * 4 + r] = pz[m][r];
    }
    __syncthreads();

    if (tid < 64) {
        const int e = e0 + tid;
        const float z = zp[tid] + zp[64 + tid] + zp[128 + tid] + zp[192 + tid] + *b2p;
        scores[e] = 1.0f / (1.0f + expf(-z));
        bool deferred = false;
        if (fabsf(z) < TAU) {
            const int slot = atomicAdd(flagCount, 1);
            if (slot < flagCap) { flagList[slot] = e; deferred = true; }
        }
        if (!deferred && z > 0.0f) {
            atomicMax(&last[srcIdx[e]], e + 1);
            atomicMax(&last[dstIdx[e]], e + 1);
        }
    }
}

// ---------------------------------------------------------------------------
// Stage B: fp32 refine, tiled (64 flagged edges/block so W1 is amortized).
// ---------------------------------------------------------------------------
__global__ __launch_bounds__(256) void refine32_kernel(
    const float* __restrict__ emb,
    const int* __restrict__ srcIdx, const int* __restrict__ dstIdx,
    const float* __restrict__ W1, const float* __restrict__ b1,
    const float* __restrict__ W2, const float* __restrict__ b2p,
    int* __restrict__ last,
    const int* __restrict__ flagCount, const int* __restrict__ flagList, int flagCap,
    int* __restrict__ flagCount2, int* __restrict__ flagList2, int flagCap2)
{
    __shared__ __align__(16) float P[RT * PST];
    __shared__ int eL[RT];
    const int tid = threadIdx.x;
    const int cnt = min(*flagCount, flagCap);
    const int nTiles = (cnt + RT - 1) / RT;
    const float b2v = *b2p;

    for (int T = blockIdx.x; T < nTiles; T += gridDim.x) {
        if (tid < RT) {
            const int idx = T * RT + tid;
            eL[tid] = flagList[min(idx, cnt - 1)];
        }
        __syncthreads();
        {
            const int i = tid >> 2, q = tid & 3;
            const int e = eL[i];
            const int node = (q < 2) ? srcIdx[e] : dstIdx[e];
            const float4* s4 = (const float4*)(emb + (size_t)node * DD + (q & 1) * 64);
            float4* d4 = (float4*)(P + i * PST + q * 64);
#pragma unroll
            for (int t = 0; t < 16; ++t) d4[t] = s4[t];
        }
        __syncthreads();

        const int rowg = tid >> 5;
        const int colg = tid & 31;
        const int c0 = colg * 8;

        float acc[8][8];
#pragma unroll
        for (int c = 0; c < 8; ++c) {
            const float bv = b1[c0 + c];
#pragma unroll
            for (int r = 0; r < 8; ++r) acc[r][c] = bv;
        }
        for (int kk = 0; kk < K2D; kk += 4) {
            float af[8][4];
#pragma unroll
            for (int r = 0; r < 8; ++r) {
                const float4 v = *(const float4*)&P[(rowg * 8 + r) * PST + kk];
                af[r][0] = v.x; af[r][1] = v.y; af[r][2] = v.z; af[r][3] = v.w;
            }
#pragma unroll
            for (int dk = 0; dk < 4; ++dk) {
                const float4 w0 = *(const float4*)&W1[(kk + dk) * HH + c0];
                const float4 w1 = *(const float4*)&W1[(kk + dk) * HH + c0 + 4];
#pragma unroll
                for (int r = 0; r < 8; ++r) {
                    const float av = af[r][dk];
                    acc[r][0] = fmaf(av, w0.x, acc[r][0]);
                    acc[r][1] = fmaf(av, w0.y, acc[r][1]);
                    acc[r][2] = fmaf(av, w0.z, acc[r][2]);
                    acc[r][3] = fmaf(av, w0.w, acc[r][3]);
                    acc[r][4] = fmaf(av, w1.x, acc[r][4]);
                    acc[r][5] = fmaf(av, w1.y, acc[r][5]);
                    acc[r][6] = fmaf(av, w1.z, acc[r][6]);
                    acc[r][7] = fmaf(av, w1.w, acc[r][7]);
                }
            }
        }

        float w2[8];
#pragma unroll
        for (int c = 0; c < 8; ++c) w2[c] = W2[c0 + c];
        float pz[8];
#pragma unroll
        for (int r = 0; r < 8; ++r) {
            float s = 0.f;
#pragma unroll
            for (int c = 0; c < 8; ++c) s = fmaf(fmaxf(acc[r][c], 0.f), w2[c], s);
            pz[r] = s;
        }
#pragma unroll
        for (int m = 1; m <= 16; m <<= 1) {
#pragma unroll
            for (int r = 0; r < 8; ++r) pz[r] += __shfl_xor(pz[r], m, 64);
        }

        if (colg == 0) {
            for (int r = 0; r < 8; ++r) {
                const int row = rowg * 8 + r;
                const int idx = T * RT + row;
                if (idx < cnt) {
                    const int e = eL[row];
                    const int s = srcIdx[e], d = dstIdx[e];
                    const float z = pz[r] + b2v;
                    if (fabsf(z) < TAU2) {
                        const int slot = atomicAdd(flagCount2, 1);
                        if (slot < flagCap2) {
                            flagList2[slot] = e;
                        } else if (z > 0.f) {
                            atomicMax(&last[s], e + 1);
                            atomicMax(&last[d], e + 1);
                        }
                    } else if (z > 0.f) {
                        atomicMax(&last[s], e + 1);
                        atomicMax(&last[d], e + 1);
                    }
                }
            }
        }
        __syncthreads();
    }
}

// ---------------------------------------------------------------------------
// Stage C: fp64 final decision for the remaining ~dozens of edges.
// ---------------------------------------------------------------------------
__global__ __launch_bounds__(256) void refine64_kernel(
    const float* __restrict__ emb,
    const int* __restrict__ srcIdx, const int* __restrict__ dstIdx,
    const float* __restrict__ W1, const float* __restrict__ b1,
    const float* __restrict__ W2, const float* __restrict__ b2p,
    int* __restrict__ last,
    const int* __restrict__ flagCount2, const int* __restrict__ flagList2,
    int flagCap2)
{
    __shared__ float pair[K2D];
    __shared__ double wsumd[4];
    const int tid = threadIdx.x;
    const int cnt = min(*flagCount2, flagCap2);
    for (int f = blockIdx.x; f < cnt; f += gridDim.x) {
        const int e = flagList2[f];
        const int s = srcIdx[e], d = dstIdx[e];
        __syncthreads();
        pair[tid] = (tid < DD) ? emb[(size_t)s * DD + tid]
                               : emb[(size_t)d * DD + tid - DD];
        __syncthreads();
        double h0 = 0.0, h1 = 0.0;
        for (int k = 0; k < K2D; k += 2) {
            h0 += (double)pair[k]     * (double)W1[(k)     * HH + tid];
            h1 += (double)pair[k + 1] * (double)W1[(k + 1) * HH + tid];
        }
        const double h = (double)b1[tid] + h0 + h1;
        double v = (h > 0.0) ? h * (double)W2[tid] : 0.0;
#pragma unroll
        for (int m = 1; m <= 32; m <<= 1) v += __shfl_xor(v, m, 64);
        if ((tid & 63) == 0) wsumd[tid >> 6] = v;
        __syncthreads();
        if (tid == 0) {
            const double z = wsumd[0] + wsumd[1] + wsumd[2] + wsumd[3] + (double)(*b2p);
            if (z > 0.0) {
                atomicMax(&last[s], e + 1);
                atomicMax(&last[d], e + 1);
            }
        }
        __syncthreads();
    }
}

// ---------------------------------------------------------------------------
// Resolver per NODE (winning edge only), both layers bf16 MFMA.
// ---------------------------------------------------------------------------
template<int BF>
__global__ __launch_bounds__(256) void res_kernel(
    const float* __restrict__ emb, const ushort* __restrict__ embbf,
    const int* __restrict__ srcIdx, const int* __restrict__ dstIdx,
    const ushort* __restrict__ w1s, const float* __restrict__ b1,
    const ushort* __restrict__ w2s, const float* __restrict__ b2,
    const int* __restrict__ last,
    float* __restrict__ outRes)
{
    __shared__ __align__(16) ushort A_lds[TE * K2D];
    __shared__ int lastL[TE];
    const int tid = threadIdx.x;
    const int n0 = blockIdx.x * TE;
    const int wv = tid >> 6;
    const int lane = tid & 63;

    if (tid < TE) {
        const int n = n0 + tid;
        lastL[tid] = (n < NN) ? last[n] : 0;
    }
    if (BF) {
        const int r = wv * 16 + (lane & 15);
        const int n = n0 + r;
        int e = 0;
        if (n < NN) { const int lv = last[n]; if (lv > 0) e = lv - 1; }
        const int ns = srcIdx[e], nd = dstIdx[e];
        const int ko = (lane >> 4) * 8;
#pragma unroll
        for (int s = 0; s < 8; ++s) {
            const int node = (s < 4) ? ns : nd;
            const ushort* g = embbf + (size_t)node * DD + (s & 3) * 32 + ko;
            __builtin_amdgcn_global_load_lds((const g1_void_t*)g,
                                             (lds_void_t*)&A_lds[(wv * 8 + s) * 512],
                                             16, 0, 0);
        }
    } else {
        const int r = tid >> 2, q = tid & 3;
        const int n = n0 + r;
        int e = 0;
        if (n < NN) { const int l = last[n]; if (l > 0) e = l - 1; }
        const int node = (q < 2) ? srcIdx[e] : dstIdx[e];
        const float4* s4 = (const float4*)(emb + (size_t)node * DD + (q & 1) * 64);
#pragma unroll
        for (int u = 0; u < 16; ++u) {
            const float4 v = s4[u];
            const int k0 = q * 64 + u * 4;
            uint2 p;
            p.x = (uint)f2bf(v.x) | ((uint)f2bf(v.y) << 16);
            p.y = (uint)f2bf(v.z) | ((uint)f2bf(v.w) << 16);
            *(uint2*)&A_lds[stageOff(r, k0)] = p;
        }
    }
    __syncthreads();

    const int lc = lane & 15, lg = lane >> 4;

    f32x4 acc[4][4] = {};
    {
        const ushort* wbase = w1s + (size_t)(wv * 4) * 8 * 512;
#pragma unroll 2
        for (int t = 0; t < 8; ++t) {
            bf16x8 af[4], bfr[4];
#pragma unroll
            for (int m = 0; m < 4; ++m)
                af[m] = *(const bf16x8*)&A_lds[(m * 8 + t) * 512 + lane * 8];
#pragma unroll
            for (int n = 0; n < 4; ++n)
                bfr[n] = *(const bf16x8*)(wbase + (n * 8 + t) * 512 + lane * 8);
#pragma unroll
            for (int m = 0; m < 4; ++m)
#pragma unroll
                for (int n = 0; n < 4; ++n)
                    acc[m][n] = __builtin_amdgcn_mfma_f32_16x16x32_bf16(af[m], bfr[n], acc[m][n], 0, 0, 0);
        }
    }
    float b1v[4];
#pragma unroll
    for (int n = 0; n < 4; ++n) b1v[n] = b1[wv * 64 + n * 16 + lc];

    __syncthreads();
#pragma unroll
    for (int m = 0; m < 4; ++m)
#pragma unroll
        for (int n = 0; n < 4; ++n) {
            const int hcol = wv * 64 + n * 16 + lc;
#pragma unroll
            for (int r = 0; r < 4; ++r) {
                const int row = m * 16 + lg * 4 + r;
                A_lds[stageOff(row, hcol)] = f2bf(fmaxf(acc[m][n][r] + b1v[n], 0.f));
            }
        }
    __syncthreads();

    f32x4 acc2[4][2] = {};
    {
        const ushort* wbase = w2s + (size_t)(wv * 2) * 8 * 512;
#pragma unroll 2
        for (int t = 0; t < 8; ++t) {
            bf16x8 af[4], bfr[2];
#pragma unroll
            for (int m = 0; m < 4; ++m)
                af[m] = *(const bf16x8*)&A_lds[(m * 8 + t) * 512 + lane * 8];
#pragma unroll
            for (int n = 0; n < 2; ++n)
                bfr[n] = *(const bf16x8*)(wbase + (n * 8 + t) * 512 + lane * 8);
#pragma unroll
            for (int m = 0; m < 4; ++m)
#pragma unroll
                for (int n = 0; n < 2; ++n)
                    acc2[m][n] = __builtin_amdgcn_mfma_f32_16x16x32_bf16(af[m], bfr[n], acc2[m][n], 0, 0, 0);
        }
    }
    float b2v[2];
#pragma unroll
    for (int n = 0; n < 2; ++n) b2v[n] = b2[(wv * 2 + n) * 16 + lc];

#pragma unroll
    for (int m = 0; m < 4; ++m)
#pragma unroll
        for (int r = 0; r < 4; ++r) {
            const int row = m * 16 + lg * 4 + r;
            const int n = n0 + row;
            if (n >= NN) continue;
            const bool hit = lastL[row] > 0;
#pragma unroll
            for (int c = 0; c < 2; ++c) {
                const int col = (wv * 2 + c) * 16 + lc;
                const float ev = emb[(size_t)n * DD + col];
                outRes[(size_t)n * DD + col] =
                    hit ? (ev + acc2[m][c][r] + b2v[c]) * 0.5f : ev;
            }
        }
}

// ---------------------------------------------------------------------------
extern "C" void kernel_launch(void* const* d_in, const int* in_sizes, int n_in,
                              void* d_out, int out_size, void* d_ws, size_t ws_size,
                              hipStream_t stream)
{
    const float* emb = (const float*)d_in[0];
    const int*   edge = (const int*)d_in[1];
    const float* Wd1 = (const float*)d_in[2];
    const float* bd1 = (const float*)d_in[3];
    const float* Wd2 = (const float*)d_in[4];
    const float* bd2 = (const float*)d_in[5];
    const float* Wr1 = (const float*)d_in[6];
    const float* br1 = (const float*)d_in[7];
    const float* Wr2 = (const float*)d_in[8];
    const float* br2 = (const float*)d_in[9];

    const int* srcIdx = edge;
    const int* dstIdx = edge + EE;

    float* outRes = (float*)d_out;
    float* scores = outRes + (size_t)NN * DD;

    // ws layout: last[50000+pad] | counters | bf16 weights | flagLists | embbf
    int* last = (int*)d_ws;
    int* flagCount  = last + 50112;
    int* flagCount2 = last + 50113;
    ushort* wd1s = (ushort*)(last + 50176);       // 128 KB
    ushort* wr1s = wd1s + 65536;                  // 128 KB
    ushort* wr2s = wr1s + 65536;                  // 64 KB
    int* flagList  = (int*)(wr2s + 32768);
    int* flagList2 = flagList + 65536;
    ushort* embbf  = (ushort*)(flagList2 + 8192); // 12.8 MB, 16B-aligned
    const size_t needBF = (size_t)(205824) * 4 + (size_t)NN * DD * 2;
    const int useBF = (ws_size >= needBF) ? 1 : 0;

    long wsInts = (long)(ws_size / 4);
    long avail = wsInts - (50176 + (65536 + 65536 + 32768) / 2);
    int flagCap  = 65536;
    int flagCap2 = 8192;
    if (avail < 65536 + 8192) {
        flagCap  = avail > 8192 ? (int)(avail - 8192) : 0;
        flagCap2 = avail > 8192 ? 8192 : (avail < 0 ? 0 : (int)avail);
    }

    hipMemsetAsync(d_ws, 0, 50176 * sizeof(int), stream);   // last + counters

    if (useBF)
        conv_kernel<<<(NN * DD / 8 + 255) / 256, 256, 0, stream>>>(emb, embbf);
    swz_kernel<<<128, 64, 0, stream>>>(Wd1, wd1s, HH, 8);
    swz_kernel<<<128, 64, 0, stream>>>(Wr1, wr1s, HH, 8);
    swz_kernel<<<64, 64, 0, stream>>>(Wr2, wr2s, DD, 8);

    if (useBF) {
        det_kernel<1><<<EE / TE, 256, 0, stream>>>(emb, embbf, srcIdx, dstIdx,
                                                   wd1s, bd1, Wd2, bd2,
                                                   scores, last, flagCount, flagList, flagCap);
    } else {
        det_kernel<0><<<EE / TE, 256, 0, stream>>>(emb, embbf, srcIdx, dstIdx,
                                                   wd1s, bd1, Wd2, bd2,
                                                   scores, last, flagCount, flagList, flagCap);
    }
    refine32_kernel<<<512, 256, 0, stream>>>(emb, srcIdx, dstIdx,
                                             Wd1, bd1, Wd2, bd2,
                                             last, flagCount, flagList, flagCap,
                                             flagCount2, flagList2, flagCap2);
    refine64_kernel<<<512, 256, 0, stream>>>(emb, srcIdx, dstIdx,
                                             Wd1, bd1, Wd2, bd2,
                                             last, flagCount2, flagList2, flagCap2);
    if (useBF) {
        res_kernel<1><<<(NN + TE - 1) / TE, 256, 0, stream>>>(emb, embbf, srcIdx, dstIdx,
                                                              wr1s, br1, wr2s, br2,
                                                              last, outRes);
    } else {
        res_kernel<0><<<(NN + TE - 1) / TE, 256, 0, stream>>>(emb, embbf, srcIdx, dstIdx,
                                                              wr1s, br1, wr2s, br2,
                                                              last, outRes);
    }
}